// Round 13
// baseline (94.609 us; speedup 1.0000x reference)
//
#include <hip/hip_runtime.h>
#include <hip/hip_bf16.h>

// ConvEncoder: emb gather (padding_idx=0) + WIN=5 im2col + Linear(640->128) + exact GELU
// dtypes: x int32, emb/W/b float32, OUTPUT float32.
// Round 13: push occupancy 16 -> 32 waves/CU (the only monotone lever measured:
// 4w=44.5us, 8w=~36, 16w=~25). MTILE=64 x NTILE=64, 512-thr blocks (8 waves,
// wave tile 16x32, acc[2] = 8 VGPRs), grid (512,2)=1024 = 4 blocks/CU x 8 waves.
// LDS 35.9 KB (4x fits 160K). __launch_bounds__(512,8) caps VGPR at 64.
// Barrier scheme, layouts, staging identical to R12 (proven).

#define EMB   128
#define WIN   5
#define OUTC  128
#define SEQ   2048
#define KTOT  640
#define MTILE 64
#define NTILE 64
#define BLK   512

#define EMB_STRIDE 136   // elems; 272-B rows; 16-row-strided b128 reads 2-way aliased (free)
#define SW_STRIDE  136
#define NCH_E ((MTILE + WIN - 1) * 16)   // 1088 16-B chunks of sEmb

typedef __bf16  bf16x8 __attribute__((ext_vector_type(8)));
typedef float   f32x4  __attribute__((ext_vector_type(4)));
typedef ushort  u16x8  __attribute__((ext_vector_type(8)));

__device__ inline ushort f2bf(float f) {
    __bf16 h = (__bf16)f;  // RNE
    return __builtin_bit_cast(ushort, h);
}

__device__ inline u16x8 cvt8v(float4 v0, float4 v1) {
    u16x8 o;
    o[0] = f2bf(v0.x); o[1] = f2bf(v0.y); o[2] = f2bf(v0.z); o[3] = f2bf(v0.w);
    o[4] = f2bf(v1.x); o[5] = f2bf(v1.y); o[6] = f2bf(v1.z); o[7] = f2bf(v1.w);
    return o;
}

__global__ __launch_bounds__(BLK, 8) void conv_encoder_kernel(
    const int* __restrict__ x,                 // (16, 2048)
    const float* __restrict__ emb,             // (50257, 128), row 0 zero
    const float* __restrict__ W,               // (128, 640)
    const float* __restrict__ bias,            // (128,)
    float* __restrict__ out)                   // (32768, 128)
{
    __shared__ ushort sEmb[(MTILE + WIN - 1) * EMB_STRIDE]; // 68 rows, 18.5 KB
    __shared__ ushort sW[NTILE * SW_STRIDE];                // 64 rows x 128-k window, 17.4 KB

    const int tid = threadIdx.x;
    const int m0  = blockIdx.x * MTILE;
    const int n0  = blockIdx.y * NTILE;    // N-pair blocks 512 apart -> same XCD (%8)
    const int bb  = m0 >> 11;
    const int s0  = m0 & (SEQ - 1);

    // ---- Window-0 W prefetch first (independent of gather chain): 2 chunks/thread ----
    float4 preA[2], preB[2];
    #pragma unroll
    for (int t = 0; t < 2; ++t) {
        const int idx = tid + t * BLK;
        const int r = idx >> 4, c = idx & 15;
        const float* p = W + (size_t)(n0 + r) * KTOT + c * 8;
        preA[t] = *(const float4*)p;
        preB[t] = *(const float4*)(p + 4);
    }

    // ---- Stage embeddings (68 rows x 128 elems), gather + cvt f32->bf16 ----
    {
        const int xbase = bb * SEQ;
        int toks[3];
        #pragma unroll
        for (int u = 0; u < 3; ++u) {           // all token loads issued up front
            const int idx = tid + u * BLK;
            if (idx < NCH_E) {
                const int s = s0 - 2 + (idx >> 4);
                toks[u] = (s >= 0 && s < SEQ) ? x[xbase + s] : 0;
            }
        }
        #pragma unroll
        for (int u = 0; u < 3; ++u) {           // emb load + cvt + LDS write
            const int idx = tid + u * BLK;
            if (idx < NCH_E) {
                const float* p = emb + (size_t)toks[u] * EMB + (idx & 15) * 8;
                *(u16x8*)(&sEmb[(idx >> 4) * EMB_STRIDE + (idx & 15) * 8]) =
                    cvt8v(*(const float4*)p, *(const float4*)(p + 4));
            }
        }
    }

    const int lane = tid & 63;
    const int wv   = tid >> 6;         // 0..7
    const int qr   = (wv >> 1) * 16;   // wave row group (0,16,32,48)
    const int qc   = (wv & 1) * 32;    // wave col half (0,32)
    const int lr   = lane & 15;
    const int lk8  = (lane >> 4) * 8;

    f32x4 acc[2];
    #pragma unroll
    for (int j = 0; j < 2; ++j)
        acc[j] = (f32x4){0.f, 0.f, 0.f, 0.f};

    for (int win = 0; win < WIN; ++win) {
        __syncthreads();   // A: prior sW reads done (win 0: pairs with B for sEmb)
        #pragma unroll
        for (int t = 0; t < 2; ++t) {
            const int idx = tid + t * BLK;
            const int r = idx >> 4, c = idx & 15;
            *(u16x8*)(&sW[r * SW_STRIDE + c * 8]) = cvt8v(preA[t], preB[t]);
        }
        __syncthreads();   // B: sW (and, at win 0, sEmb) visible

        // Next window's W loads fly through the MFMA region; drained at next A.
        if (win + 1 < WIN) {
            #pragma unroll
            for (int t = 0; t < 2; ++t) {
                const int idx = tid + t * BLK;
                const int r = idx >> 4, c = idx & 15;
                const float* p = W + (size_t)(n0 + r) * KTOT + (win + 1) * EMB + c * 8;
                preA[t] = *(const float4*)p;
                preB[t] = *(const float4*)(p + 4);
            }
        }

        #pragma unroll
        for (int kc = 0; kc < 4; ++kc) {
            const int e = kc * 32 + lk8;
            bf16x8 afr, bfr[2];
            afr = *(const bf16x8*)(&sEmb[(qr + lr + win) * EMB_STRIDE + e]);
            #pragma unroll
            for (int j = 0; j < 2; ++j)
                bfr[j] = *(const bf16x8*)(&sW[(qc + j * 16 + lr) * SW_STRIDE + e]);
            #pragma unroll
            for (int j = 0; j < 2; ++j)
                acc[j] = __builtin_amdgcn_mfma_f32_16x16x32_bf16(afr, bfr[j], acc[j], 0, 0, 0);
        }
    }

    // ---- Epilogue: bias + exact GELU + fp32 store ----
    float bj[2];
    #pragma unroll
    for (int j = 0; j < 2; ++j)
        bj[j] = bias[n0 + qc + j * 16 + lr];

    const int rbase = (lane >> 4) * 4;
    #pragma unroll
    for (int j = 0; j < 2; ++j) {
        const int col = n0 + qc + j * 16 + lr;
        #pragma unroll
        for (int r = 0; r < 4; ++r) {
            const int row = m0 + qr + rbase + r;
            const float y = acc[j][r] + bj[j];
            const float g = 0.5f * y * (1.0f + erff(y * 0.70710678118654752f));
            out[(size_t)row * OUTC + col] = g;
        }
    }
}

extern "C" void kernel_launch(void* const* d_in, const int* in_sizes, int n_in,
                              void* d_out, int out_size, void* d_ws, size_t ws_size,
                              hipStream_t stream) {
    (void)in_sizes; (void)n_in; (void)d_ws; (void)ws_size; (void)out_size;
    const int* x        = (const int*)d_in[0];
    const float* emb    = (const float*)d_in[1];
    const float* Wm     = (const float*)d_in[2];
    const float* bias   = (const float*)d_in[3];
    float* out          = (float*)d_out;

    dim3 grid(32768 / MTILE, OUTC / NTILE);   // (512,2) = 1024 blocks -> 4/CU, 32 waves/CU
    dim3 block(BLK);
    hipLaunchKernelGGL(conv_encoder_kernel, grid, block, 0, stream, x, emb, Wm, bias, out);
}

// Round 14
// 89.498 us; speedup vs baseline: 1.0571x; 1.0571x over previous
//
#include <hip/hip_runtime.h>
#include <hip/hip_bf16.h>

// ConvEncoder: emb gather (padding_idx=0) + WIN=5 im2col + Linear(640->128) + exact GELU
// dtypes: x int32, emb/W/b float32, OUTPUT float32.
// Round 14: R12 geometry (MTILE=128 x NTILE=64, 512 thr, grid(256,2) -> 2 blk/CU
// x 8 waves = 16 waves/CU, the measured optimum) + ping-pong sW:
//   - 5 barriers total (was 10): one initial, one per window transition.
//   - W(win+1) loads issued AFTER each barrier -> fly through the MFMA region;
//     their vmcnt wait lands at the sW write AFTER compute (no barrier drains
//     freshly issued loads).

#define EMB   128
#define WIN   5
#define OUTC  128
#define SEQ   2048
#define KTOT  640
#define MTILE 128
#define NTILE 64
#define BLK   512

#define EMB_STRIDE 136   // elems; 272-B rows; 16-row-strided b128 reads 2-way aliased (free)
#define SW_STRIDE  136
#define NCH_E ((MTILE + WIN - 1) * 16)   // 2112 16-B chunks of sEmb

typedef __bf16  bf16x8 __attribute__((ext_vector_type(8)));
typedef float   f32x4  __attribute__((ext_vector_type(4)));
typedef ushort  u16x8  __attribute__((ext_vector_type(8)));

__device__ inline ushort f2bf(float f) {
    __bf16 h = (__bf16)f;  // RNE
    return __builtin_bit_cast(ushort, h);
}

__device__ inline u16x8 cvt8v(float4 v0, float4 v1) {
    u16x8 o;
    o[0] = f2bf(v0.x); o[1] = f2bf(v0.y); o[2] = f2bf(v0.z); o[3] = f2bf(v0.w);
    o[4] = f2bf(v1.x); o[5] = f2bf(v1.y); o[6] = f2bf(v1.z); o[7] = f2bf(v1.w);
    return o;
}

__global__ __launch_bounds__(BLK, 4) void conv_encoder_kernel(
    const int* __restrict__ x,                 // (16, 2048)
    const float* __restrict__ emb,             // (50257, 128), row 0 zero
    const float* __restrict__ W,               // (128, 640)
    const float* __restrict__ bias,            // (128,)
    float* __restrict__ out)                   // (32768, 128)
{
    __shared__ ushort sEmb[(MTILE + WIN - 1) * EMB_STRIDE]; // 132 rows, 35.9 KB
    __shared__ ushort sW[2][NTILE * SW_STRIDE];             // ping-pong, 2 x 17.4 KB

    const int tid = threadIdx.x;
    const int m0  = blockIdx.x * MTILE;
    const int n0  = blockIdx.y * NTILE;    // N-pair 256 blocks apart -> same XCD (%8)
    const int bb  = m0 >> 11;
    const int s0  = m0 & (SEQ - 1);

    // ---- Window-0 W loads first (independent of gather chain) ----
    float4 preA[2], preB[2];
    #pragma unroll
    for (int t = 0; t < 2; ++t) {
        const int idx = tid + t * BLK;
        const int r = idx >> 4, c = idx & 15;
        const float* p = W + (size_t)(n0 + r) * KTOT + c * 8;
        preA[t] = *(const float4*)p;
        preB[t] = *(const float4*)(p + 4);
    }

    // ---- Stage embeddings (132 rows x 128 elems), gather + cvt f32->bf16 ----
    {
        const int xbase = bb * SEQ;
        int toks[5];
        #pragma unroll
        for (int u = 0; u < 5; ++u) {           // all token loads issued up front
            const int idx = tid + u * BLK;
            if (idx < NCH_E) {
                const int s = s0 - 2 + (idx >> 4);
                toks[u] = (s >= 0 && s < SEQ) ? x[xbase + s] : 0;
            }
        }
        #pragma unroll
        for (int u = 0; u < 5; ++u) {           // emb load + cvt + LDS write
            const int idx = tid + u * BLK;
            if (idx < NCH_E) {
                const float* p = emb + (size_t)toks[u] * EMB + (idx & 15) * 8;
                *(u16x8*)(&sEmb[(idx >> 4) * EMB_STRIDE + (idx & 15) * 8]) =
                    cvt8v(*(const float4*)p, *(const float4*)(p + 4));
            }
        }
    }

    // ---- Write window-0 W into sW[0] (pre-barrier, alongside sEmb staging) ----
    #pragma unroll
    for (int t = 0; t < 2; ++t) {
        const int idx = tid + t * BLK;
        const int r = idx >> 4, c = idx & 15;
        *(u16x8*)(&sW[0][r * SW_STRIDE + c * 8]) = cvt8v(preA[t], preB[t]);
    }
    __syncthreads();   // barrier 1 of 5: sEmb + sW[0] visible

    const int lane = tid & 63;
    const int wv   = tid >> 6;         // 0..7
    const int qr   = (wv >> 1) * 32;   // wave row quadrant (0,32,64,96)
    const int qc   = (wv & 1) * 32;    // wave col half (0,32)
    const int lr   = lane & 15;
    const int lk8  = (lane >> 4) * 8;

    f32x4 acc[2][2];
    #pragma unroll
    for (int i = 0; i < 2; ++i)
        #pragma unroll
        for (int j = 0; j < 2; ++j)
            acc[i][j] = (f32x4){0.f, 0.f, 0.f, 0.f};

    #pragma unroll
    for (int win = 0; win < WIN; ++win) {
        const int buf = win & 1;

        // Issue W(win+1) loads post-barrier: they fly through the MFMA region.
        if (win + 1 < WIN) {
            #pragma unroll
            for (int t = 0; t < 2; ++t) {
                const int idx = tid + t * BLK;
                const int r = idx >> 4, c = idx & 15;
                const float* p = W + (size_t)(n0 + r) * KTOT + (win + 1) * EMB + c * 8;
                preA[t] = *(const float4*)p;
                preB[t] = *(const float4*)(p + 4);
            }
        }

        // ---- Compute window from sW[buf] ----
        #pragma unroll
        for (int kc = 0; kc < 4; ++kc) {
            const int e = kc * 32 + lk8;
            bf16x8 afr[2], bfr[2];
            #pragma unroll
            for (int i = 0; i < 2; ++i)
                afr[i] = *(const bf16x8*)(&sEmb[(qr + i * 16 + lr + win) * EMB_STRIDE + e]);
            #pragma unroll
            for (int j = 0; j < 2; ++j)
                bfr[j] = *(const bf16x8*)(&sW[buf][(qc + j * 16 + lr) * SW_STRIDE + e]);
            #pragma unroll
            for (int i = 0; i < 2; ++i)
                #pragma unroll
                for (int j = 0; j < 2; ++j)
                    acc[i][j] = __builtin_amdgcn_mfma_f32_16x16x32_bf16(afr[i], bfr[j], acc[i][j], 0, 0, 0);
        }

        // ---- Write next window into the OTHER buffer; vmcnt wait lands here ----
        if (win + 1 < WIN) {
            #pragma unroll
            for (int t = 0; t < 2; ++t) {
                const int idx = tid + t * BLK;
                const int r = idx >> 4, c = idx & 15;
                *(u16x8*)(&sW[1 - buf][r * SW_STRIDE + c * 8]) = cvt8v(preA[t], preB[t]);
            }
            __syncthreads();   // barriers 2..5
        }
    }

    // ---- Epilogue: bias + exact GELU + fp32 store ----
    float bj[2];
    #pragma unroll
    for (int j = 0; j < 2; ++j)
        bj[j] = bias[n0 + qc + j * 16 + lr];

    const int rbase = (lane >> 4) * 4;
    #pragma unroll
    for (int i = 0; i < 2; ++i) {
        #pragma unroll
        for (int j = 0; j < 2; ++j) {
            const int col = n0 + qc + j * 16 + lr;
            #pragma unroll
            for (int r = 0; r < 4; ++r) {
                const int row = m0 + qr + i * 16 + rbase + r;
                const float y = acc[i][j][r] + bj[j];
                const float g = 0.5f * y * (1.0f + erff(y * 0.70710678118654752f));
                out[(size_t)row * OUTC + col] = g;
            }
        }
    }
}

extern "C" void kernel_launch(void* const* d_in, const int* in_sizes, int n_in,
                              void* d_out, int out_size, void* d_ws, size_t ws_size,
                              hipStream_t stream) {
    (void)in_sizes; (void)n_in; (void)d_ws; (void)ws_size; (void)out_size;
    const int* x        = (const int*)d_in[0];
    const float* emb    = (const float*)d_in[1];
    const float* Wm     = (const float*)d_in[2];
    const float* bias   = (const float*)d_in[3];
    float* out          = (float*)d_out;

    dim3 grid(32768 / MTILE, OUTC / NTILE);   // (256,2) = 512 blocks -> 2/CU, 16 waves/CU
    dim3 block(BLK);
    hipLaunchKernelGGL(conv_encoder_kernel, grid, block, 0, stream, x, emb, Wm, bias, out);
}